// Round 4
// baseline (136.904 us; speedup 1.0000x reference)
//
#include <hip/hip_runtime.h>
#include <math.h>

#define BATCH   256
#define NBLK    5000
#define NBLKP   5024      // padded row stride for g (fp32 stage-1 output)
#define IN_DIM  400000
#define D1      1024
#define D2      256
#define K1P     5120      // K for GEMM1, padded to multiple of 64
#define NSPLIT  8
#define KSPLIT  (K1P / NSPLIT)   // 640 -> 10 BK=64 steps per split

#define CONV_BLKS   (D1 + D2 * D1 / 1024)          // 1280
#define SPARSE_BLKS ((NBLKP + 63) / 64 * BATCH)    // 79*256

typedef __attribute__((ext_vector_type(8))) short short8_t;
typedef __attribute__((ext_vector_type(4))) float f32x4;

static __device__ __forceinline__ unsigned short f2bf(float f) {
    union { float f; unsigned int u; } v; v.f = f;
    unsigned int u = v.u;
    return (unsigned short)((u + 0x7FFFu + ((u >> 16) & 1u)) >> 16);   // RNE
}

// ---------------------------------------------------------------------------
// Stage 1 merged: W1/W2 fp32->bf16 conversion (blocks [0,1280)) and the
// sparse block dot products (remaining blocks). Conv traffic (~32 MB)
// overlaps the HBM-bound x stream (~410 MB).
// ---------------------------------------------------------------------------
__global__ __launch_bounds__(256) void k_stage1(const float* __restrict__ x,
                                                const float* __restrict__ sv,
                                                float* __restrict__ g,
                                                const float* __restrict__ W1,
                                                unsigned short* __restrict__ W1b,
                                                const float* __restrict__ W2,
                                                unsigned short* __restrict__ W2b) {
    const int id  = blockIdx.x;
    const int tid = threadIdx.x;
    if (id < CONV_BLKS) {
        if (id < D1) {                       // W1 row conv [1024][5000] -> [1024][5120]
            const float* src = W1 + (size_t)id * NBLK;
            unsigned short* dst = W1b + (size_t)id * K1P;
            for (int c4 = tid; c4 < K1P / 4; c4 += 256) {
                const int c = c4 * 4;
                ushort4 o;
                if (c < NBLK) {
                    float4 v = *reinterpret_cast<const float4*>(src + c);
                    o = { f2bf(v.x), f2bf(v.y), f2bf(v.z), f2bf(v.w) };
                } else {
                    o = ushort4{0, 0, 0, 0};
                }
                *reinterpret_cast<ushort4*>(dst + c) = o;
            }
        } else {                             // W2 conv [256][1024]
            const int idx = ((id - D1) * 256 + tid) * 4;
            float4 v = *reinterpret_cast<const float4*>(W2 + idx);
            ushort4 o = { f2bf(v.x), f2bf(v.y), f2bf(v.z), f2bf(v.w) };
            *reinterpret_cast<ushort4*>(W2b + idx) = o;
        }
        return;
    }
    // sparse part: g[b][j] = dot(x[b, 80j:80j+80], sv[80j:80j+80])
    const int rem = id - CONV_BLKS;
    const int b   = rem / ((NBLKP + 63) / 64);
    const int bx  = rem % ((NBLKP + 63) / 64);
    const int jj  = tid >> 2;
    const int s   = tid & 3;
    const int j   = bx * 64 + jj;
    if (j >= NBLK) return;
    const float4* xr = reinterpret_cast<const float4*>(x + (size_t)b * IN_DIM + (size_t)j * 80);
    const float4* sr = reinterpret_cast<const float4*>(sv + (size_t)j * 80);
    float acc = 0.0f;
#pragma unroll
    for (int r = 0; r < 5; ++r) {
        float4 xv = xr[r * 4 + s];
        float4 sg = sr[r * 4 + s];
        acc += xv.x * sg.x + xv.y * sg.y + xv.z * sg.z + xv.w * sg.w;
    }
    acc += __shfl_xor(acc, 1);
    acc += __shfl_xor(acc, 2);
    if (s == 0) g[(size_t)b * NBLKP + j] = acc;
}

// ---------------------------------------------------------------------------
// Stage 2: LayerNorm over 5000 blocks; row cached in registers (20/thread);
// writes bf16 A [BATCH][K1P] with zero pad.
// ---------------------------------------------------------------------------
__global__ __launch_bounds__(256) void k_ln(const float* __restrict__ g,
                                            const float* __restrict__ gamma,
                                            const float* __restrict__ beta,
                                            unsigned short* __restrict__ A) {
    const int b   = blockIdx.x;
    const int tid = threadIdx.x;
    const float* row = g + (size_t)b * NBLKP;
    float v[20];
    float s = 0.0f, ss = 0.0f;
#pragma unroll
    for (int i = 0; i < 20; ++i) {
        const int j = tid + i * 256;
        const float xv = (j < NBLK) ? row[j] : 0.0f;
        v[i] = xv; s += xv; ss += xv * xv;
    }
#pragma unroll
    for (int o = 32; o > 0; o >>= 1) {
        s  += __shfl_xor(s, o);
        ss += __shfl_xor(ss, o);
    }
    __shared__ float ls[4], lss[4];
    const int wid = tid >> 6;
    if ((tid & 63) == 0) { ls[wid] = s; lss[wid] = ss; }
    __syncthreads();
    s  = ls[0] + ls[1] + ls[2] + ls[3];
    ss = lss[0] + lss[1] + lss[2] + lss[3];
    const float mu  = s / (float)NBLK;
    const float var = ss / (float)NBLK - mu * mu;
    const float rs  = rsqrtf(var + 1e-5f);
    unsigned short* dst = A + (size_t)b * K1P;
#pragma unroll
    for (int i = 0; i < 20; ++i) {
        const int j = tid + i * 256;          // max 5119 == K1P-1: covers pad
        const float val = (j < NBLK) ? ((v[i] - mu) * rs * gamma[j] + beta[j]) : 0.0f;
        dst[j] = f2bf(val);
    }
}

// ---------------------------------------------------------------------------
// GEMM1: bf16 MFMA with reg-staged prefetch, split-K partials.
// 64x64 tile, 4 waves (2x2 of 32x32), BK=64, mfma_f32_16x16x32_bf16.
// ---------------------------------------------------------------------------
__global__ __launch_bounds__(256) void k_mfma_gemm1(const unsigned short* __restrict__ A,
                                                    const unsigned short* __restrict__ W,
                                                    float* __restrict__ C,
                                                    int ksteps) {
    const int m0 = blockIdx.y * 64;
    const int n0 = blockIdx.x * 64;
    const int z  = blockIdx.z;
    const int kbase = z * ksteps * 64;
    float* Cz = C + (size_t)z * (size_t)BATCH * D1;

    __shared__ unsigned short As[64][72];
    __shared__ unsigned short Ws[64][72];

    const int tid  = threadIdx.x;
    const int wave = tid >> 6;
    const int lane = tid & 63;
    const int wr   = (wave >> 1) * 32;
    const int wc   = (wave & 1) * 32;
    const int lr   = lane & 15;
    const int lk   = (lane >> 4) * 8;
    const int srow = tid >> 3;
    const int scol = (tid & 7) * 8;

    const unsigned short* Ap = A + (size_t)(m0 + srow) * K1P + kbase + scol;
    const unsigned short* Wp = W + (size_t)(n0 + srow) * K1P + kbase + scol;

    short8_t pa0 = *reinterpret_cast<const short8_t*>(Ap);
    short8_t pa1 = *reinterpret_cast<const short8_t*>(Ap + (size_t)32 * K1P);
    short8_t pw0 = *reinterpret_cast<const short8_t*>(Wp);
    short8_t pw1 = *reinterpret_cast<const short8_t*>(Wp + (size_t)32 * K1P);

    f32x4 acc[2][2] = {};

    for (int t = 0; t < ksteps; ++t) {
        __syncthreads();
        *reinterpret_cast<short8_t*>(&As[srow][scol])      = pa0;
        *reinterpret_cast<short8_t*>(&As[srow + 32][scol]) = pa1;
        *reinterpret_cast<short8_t*>(&Ws[srow][scol])      = pw0;
        *reinterpret_cast<short8_t*>(&Ws[srow + 32][scol]) = pw1;
        __syncthreads();
        if (t + 1 < ksteps) {
            const unsigned short* An = Ap + (size_t)(t + 1) * 64;
            const unsigned short* Wn = Wp + (size_t)(t + 1) * 64;
            pa0 = *reinterpret_cast<const short8_t*>(An);
            pa1 = *reinterpret_cast<const short8_t*>(An + (size_t)32 * K1P);
            pw0 = *reinterpret_cast<const short8_t*>(Wn);
            pw1 = *reinterpret_cast<const short8_t*>(Wn + (size_t)32 * K1P);
        }
#pragma unroll
        for (int kk = 0; kk < 64; kk += 32) {
            short8_t a0 = *reinterpret_cast<const short8_t*>(&As[wr + lr][kk + lk]);
            short8_t a1 = *reinterpret_cast<const short8_t*>(&As[wr + 16 + lr][kk + lk]);
            short8_t b0 = *reinterpret_cast<const short8_t*>(&Ws[wc + lr][kk + lk]);
            short8_t b1 = *reinterpret_cast<const short8_t*>(&Ws[wc + 16 + lr][kk + lk]);
            acc[0][0] = __builtin_amdgcn_mfma_f32_16x16x32_bf16(a0, b0, acc[0][0], 0, 0, 0);
            acc[0][1] = __builtin_amdgcn_mfma_f32_16x16x32_bf16(a0, b1, acc[0][1], 0, 0, 0);
            acc[1][0] = __builtin_amdgcn_mfma_f32_16x16x32_bf16(a1, b0, acc[1][0], 0, 0, 0);
            acc[1][1] = __builtin_amdgcn_mfma_f32_16x16x32_bf16(a1, b1, acc[1][1], 0, 0, 0);
        }
    }

    const int rbase = (lane >> 4) * 4;
#pragma unroll
    for (int i = 0; i < 2; ++i)
#pragma unroll
        for (int j = 0; j < 2; ++j) {
            const int col = n0 + wc + j * 16 + lr;
#pragma unroll
            for (int r = 0; r < 4; ++r) {
                const int row = m0 + wr + i * 16 + rbase + r;
                Cz[(size_t)row * D1 + col] = acc[i][j][r];
            }
        }
}

// Sum split-K partials + b1, convert to bf16 A2 [256][1024].
__global__ __launch_bounds__(256) void k_fuse(const float* __restrict__ p,
                                              const float* __restrict__ b1,
                                              unsigned short* __restrict__ A2) {
    const int idx = (blockIdx.x * 256 + threadIdx.x) * 4;
    const int col = idx & (D1 - 1);
    const size_t S = (size_t)BATCH * D1;
    float4 bb = *reinterpret_cast<const float4*>(b1 + col);
    float sx = bb.x, sy = bb.y, sz = bb.z, sw = bb.w;
#pragma unroll
    for (int q = 0; q < NSPLIT; ++q) {
        float4 v = *reinterpret_cast<const float4*>(p + q * S + idx);
        sx += v.x; sy += v.y; sz += v.z; sw += v.w;
    }
    ushort4 o = { f2bf(sx), f2bf(sy), f2bf(sz), f2bf(sw) };
    *reinterpret_cast<ushort4*>(A2 + idx) = o;
}

// ---------------------------------------------------------------------------
// Fused tail: h2 = sigmoid(A2 @ W2^T + b2); out = h2 @ W3 + b3 — h2 never
// materialized. 8 blocks x (32 rows x 256 cols), 4 waves (wave w owns cols
// w*64..w*64+63), K=1024 in 16 BK=64 steps with reg prefetch. Each lane folds
// its accs into sum(sigmoid(.)*W3), shfl-reduces over the 16 fragment cols,
// then a 512 B LDS combine across waves.
// ---------------------------------------------------------------------------
__global__ __launch_bounds__(256) void k_tail(const unsigned short* __restrict__ A2,
                                              const unsigned short* __restrict__ W2b,
                                              const float* __restrict__ b2,
                                              const float* __restrict__ W3,
                                              const float* __restrict__ b3,
                                              float* __restrict__ out) {
    const int m0 = blockIdx.x * 32;
    __shared__ unsigned short As[32][72];
    __shared__ unsigned short Ws[256][72];
    __shared__ float red[4][32];

    const int tid  = threadIdx.x;
    const int wave = tid >> 6;
    const int lane = tid & 63;
    const int wc   = wave * 64;
    const int lr   = lane & 15;
    const int lk   = (lane >> 4) * 8;
    const int srow = tid >> 3;            // 0..31
    const int scol = (tid & 7) * 8;

    const unsigned short* Ap = A2 + (size_t)(m0 + srow) * D1 + scol;
    const unsigned short* Wp = W2b + (size_t)srow * D1 + scol;    // rows srow + it*32

    short8_t pa = *reinterpret_cast<const short8_t*>(Ap);
    short8_t pw[8];
#pragma unroll
    for (int it = 0; it < 8; ++it)
        pw[it] = *reinterpret_cast<const short8_t*>(Wp + (size_t)it * 32 * D1);

    f32x4 acc[2][4] = {};

    for (int t = 0; t < 16; ++t) {
        __syncthreads();
        *reinterpret_cast<short8_t*>(&As[srow][scol]) = pa;
#pragma unroll
        for (int it = 0; it < 8; ++it)
            *reinterpret_cast<short8_t*>(&Ws[srow + it * 32][scol]) = pw[it];
        __syncthreads();
        if (t + 1 < 16) {
            const int ko = (t + 1) * 64;
            pa = *reinterpret_cast<const short8_t*>(Ap + ko);
#pragma unroll
            for (int it = 0; it < 8; ++it)
                pw[it] = *reinterpret_cast<const short8_t*>(Wp + (size_t)it * 32 * D1 + ko);
        }
#pragma unroll
        for (int kk = 0; kk < 64; kk += 32) {
            short8_t a0 = *reinterpret_cast<const short8_t*>(&As[lr][kk + lk]);
            short8_t a1 = *reinterpret_cast<const short8_t*>(&As[16 + lr][kk + lk]);
#pragma unroll
            for (int j = 0; j < 4; ++j) {
                short8_t bj = *reinterpret_cast<const short8_t*>(&Ws[wc + j * 16 + lr][kk + lk]);
                acc[0][j] = __builtin_amdgcn_mfma_f32_16x16x32_bf16(a0, bj, acc[0][j], 0, 0, 0);
                acc[1][j] = __builtin_amdgcn_mfma_f32_16x16x32_bf16(a1, bj, acc[1][j], 0, 0, 0);
            }
        }
    }

    // epilogue: fold cols into sum(sigmoid(acc + b2[col]) * W3[col])
    float b2c[4], w3c[4];
#pragma unroll
    for (int j = 0; j < 4; ++j) {
        const int col = wc + j * 16 + lr;
        b2c[j] = b2[col];
        w3c[j] = W3[col];
    }
    const int rbase = (lane >> 4) * 4;
#pragma unroll
    for (int i = 0; i < 2; ++i) {
#pragma unroll
        for (int r = 0; r < 4; ++r) {
            float pv = 0.0f;
#pragma unroll
            for (int j = 0; j < 4; ++j) {
                const float h = acc[i][j][r] + b2c[j];
                pv += w3c[j] / (1.0f + __expf(-h));
            }
            pv += __shfl_xor(pv, 1);
            pv += __shfl_xor(pv, 2);
            pv += __shfl_xor(pv, 4);
            pv += __shfl_xor(pv, 8);
            if (lr == 0) red[wave][i * 16 + rbase + r] = pv;
        }
    }
    __syncthreads();
    if (tid < 32) {
        const float s = red[0][tid] + red[1][tid] + red[2][tid] + red[3][tid];
        out[m0 + tid] = s + b3[0];
    }
}

extern "C" void kernel_launch(void* const* d_in, const int* in_sizes, int n_in,
                              void* d_out, int out_size, void* d_ws, size_t ws_size,
                              hipStream_t stream) {
    const float* x     = (const float*)d_in[0];
    const float* sv    = (const float*)d_in[1];
    const float* gamma = (const float*)d_in[2];
    const float* beta  = (const float*)d_in[3];
    const float* W1    = (const float*)d_in[4];
    const float* b1    = (const float*)d_in[5];
    const float* W2    = (const float*)d_in[6];
    const float* b2    = (const float*)d_in[7];
    const float* W3    = (const float*)d_in[8];
    const float* b3    = (const float*)d_in[9];
    float* out = (float*)d_out;

    char* ws = (char*)d_ws;
    size_t off = 0;
    auto alloc = [&](size_t bytes) { char* p = ws + off; off = (off + bytes + 255) & ~(size_t)255; return p; };
    float*          g     = (float*)         alloc((size_t)BATCH * NBLKP * 4);
    unsigned short* Ab    = (unsigned short*)alloc((size_t)BATCH * K1P * 2);
    unsigned short* W1b   = (unsigned short*)alloc((size_t)D1 * K1P * 2);
    float*          out1p = (float*)         alloc((size_t)NSPLIT * BATCH * D1 * 4);
    unsigned short* A2b   = (unsigned short*)alloc((size_t)BATCH * D1 * 2);
    unsigned short* W2b   = (unsigned short*)alloc((size_t)D2 * D1 * 2);

    k_stage1<<<dim3(CONV_BLKS + SPARSE_BLKS), 256, 0, stream>>>(x, sv, g, W1, W1b, W2, W2b);
    k_ln<<<dim3(BATCH), 256, 0, stream>>>(g, gamma, beta, Ab);
    k_mfma_gemm1<<<dim3(D1 / 64, BATCH / 64, NSPLIT), 256, 0, stream>>>(Ab, W1b, out1p, KSPLIT / 64);
    k_fuse<<<dim3(BATCH * D1 / (256 * 4)), 256, 0, stream>>>(out1p, b1, A2b);
    k_tail<<<dim3(BATCH / 32), 256, 0, stream>>>(A2b, W2b, b2, W3, b3, out);
}

// Round 5
// 128.802 us; speedup vs baseline: 1.0629x; 1.0629x over previous
//
#include <hip/hip_runtime.h>
#include <math.h>

#define BATCH   256
#define NBLK    5000
#define NBLKP   5024      // padded row stride for g (alignment only; pad never read)
#define IN_DIM  400000
#define D1      1024
#define D2      256
#define K1P     5120      // K for GEMM1, padded to multiple of 64
#define NSPLIT  16
#define ZK      (K1P / NSPLIT)   // 320 K-elems per split
#define ZSTEPS  (ZK / 64)        // 5 BK=64 steps per split

typedef __attribute__((ext_vector_type(8))) short short8_t;
typedef __attribute__((ext_vector_type(4))) float f32x4;

static __device__ __forceinline__ unsigned short f2bf(float f) {
    union { float f; unsigned int u; } v; v.f = f;
    unsigned int u = v.u;
    return (unsigned short)((u + 0x7FFFu + ((u >> 16) & 1u)) >> 16);   // RNE
}

// ---------------------------------------------------------------------------
// Stage 1: sparse block dot products (x read once, HBM-bound).
// ---------------------------------------------------------------------------
__global__ __launch_bounds__(256) void k_sparse(const float* __restrict__ x,
                                                const float* __restrict__ sv,
                                                float* __restrict__ g) {
    const int b   = blockIdx.y;
    const int tid = threadIdx.x;
    const int jj  = tid >> 2;
    const int s   = tid & 3;
    const int j   = blockIdx.x * 64 + jj;
    if (j >= NBLK) return;
    const float4* xr = reinterpret_cast<const float4*>(x + (size_t)b * IN_DIM + (size_t)j * 80);
    const float4* sr = reinterpret_cast<const float4*>(sv + (size_t)j * 80);
    float acc = 0.0f;
#pragma unroll
    for (int r = 0; r < 5; ++r) {
        float4 xv = xr[r * 4 + s];
        float4 sg = sr[r * 4 + s];
        acc += xv.x * sg.x + xv.y * sg.y + xv.z * sg.z + xv.w * sg.w;
    }
    acc += __shfl_xor(acc, 1);
    acc += __shfl_xor(acc, 2);
    if (s == 0) g[(size_t)b * NBLKP + j] = acc;
}

// ---------------------------------------------------------------------------
// Stage 2: LayerNorm; row cached in registers; writes bf16 A [BATCH][K1P],
// zero-padded to K1P.
// ---------------------------------------------------------------------------
__global__ __launch_bounds__(256) void k_ln(const float* __restrict__ g,
                                            const float* __restrict__ gamma,
                                            const float* __restrict__ beta,
                                            unsigned short* __restrict__ A) {
    const int b   = blockIdx.x;
    const int tid = threadIdx.x;
    const float* row = g + (size_t)b * NBLKP;
    float v[20];
    float s = 0.0f, ss = 0.0f;
#pragma unroll
    for (int i = 0; i < 20; ++i) {
        const int j = tid + i * 256;
        const float xv = (j < NBLK) ? row[j] : 0.0f;
        v[i] = xv; s += xv; ss += xv * xv;
    }
#pragma unroll
    for (int o = 32; o > 0; o >>= 1) {
        s  += __shfl_xor(s, o);
        ss += __shfl_xor(ss, o);
    }
    __shared__ float ls[4], lss[4];
    const int wid = tid >> 6;
    if ((tid & 63) == 0) { ls[wid] = s; lss[wid] = ss; }
    __syncthreads();
    s  = ls[0] + ls[1] + ls[2] + ls[3];
    ss = lss[0] + lss[1] + lss[2] + lss[3];
    const float mu  = s / (float)NBLK;
    const float var = ss / (float)NBLK - mu * mu;
    const float rs  = rsqrtf(var + 1e-5f);
    unsigned short* dst = A + (size_t)b * K1P;
#pragma unroll
    for (int i = 0; i < 20; ++i) {
        const int j = tid + i * 256;          // max 5119 == K1P-1: covers pad
        const float val = (j < NBLK) ? ((v[i] - mu) * rs * gamma[j] + beta[j]) : 0.0f;
        dst[j] = f2bf(val);
    }
}

// ---------------------------------------------------------------------------
// GEMM1: M=256 (full batch) x N=64 tile, split-K=16. W1 read ONCE as fp32,
// converted to bf16 during LDS staging (no separate conv, no W1b buffer).
// 4 waves, each owns 64 rows x 64 cols: acc[4][4], 32 MFMA per K64-step.
// Reg-staged prefetch of the next step's A (bf16) and W (fp32) chunks.
// ---------------------------------------------------------------------------
__global__ __launch_bounds__(256) void k_gemm1(const unsigned short* __restrict__ A,
                                               const float* __restrict__ W1,
                                               float* __restrict__ C) {
    const int n0 = blockIdx.x * 64;
    const int z  = blockIdx.y;
    const int kbase = z * ZK;
    float* Cz = C + (size_t)z * BATCH * D1;

    __shared__ unsigned short As[256][72];   // +8 pad -> <=2-way (free) conflicts
    __shared__ unsigned short Ws[64][72];

    const int tid  = threadIdx.x;
    const int wave = tid >> 6;
    const int lane = tid & 63;
    const int lr   = lane & 15;
    const int lk   = (lane >> 4) * 8;
    const int srow = tid >> 3;            // 0..31 (A staging row base)
    const int scol = (tid & 7) * 8;       // 0..56
    const int wrow = tid >> 2;            // 0..63 (W staging row)
    const int wcol = (tid & 3) * 16;      // 0/16/32/48 (elems)

    const unsigned short* Ap = A + (size_t)srow * K1P + kbase + scol;
    const float* Wrow = W1 + (size_t)(n0 + wrow) * NBLK;

    short8_t pa[8];
    float4 pwf[4];
    auto loadA = [&](int t) {
#pragma unroll
        for (int it = 0; it < 8; ++it)
            pa[it] = *reinterpret_cast<const short8_t*>(Ap + (size_t)it * 32 * K1P + t * 64);
    };
    auto loadW = [&](int t) {
        const int k0 = kbase + t * 64 + wcol;
#pragma unroll
        for (int q = 0; q < 4; ++q) {
            const int k = k0 + q * 4;      // 4-aligned; NBLK%4==0 -> whole float4 in/out
            pwf[q] = (k < NBLK) ? *reinterpret_cast<const float4*>(Wrow + k)
                                : float4{0.f, 0.f, 0.f, 0.f};
        }
    };

    loadA(0);
    loadW(0);

    f32x4 acc[4][4] = {};

    for (int t = 0; t < ZSTEPS; ++t) {
        __syncthreads();
#pragma unroll
        for (int it = 0; it < 8; ++it)
            *reinterpret_cast<short8_t*>(&As[srow + it * 32][scol]) = pa[it];
        {
            short8_t w0 = { (short)f2bf(pwf[0].x), (short)f2bf(pwf[0].y), (short)f2bf(pwf[0].z), (short)f2bf(pwf[0].w),
                            (short)f2bf(pwf[1].x), (short)f2bf(pwf[1].y), (short)f2bf(pwf[1].z), (short)f2bf(pwf[1].w) };
            short8_t w1 = { (short)f2bf(pwf[2].x), (short)f2bf(pwf[2].y), (short)f2bf(pwf[2].z), (short)f2bf(pwf[2].w),
                            (short)f2bf(pwf[3].x), (short)f2bf(pwf[3].y), (short)f2bf(pwf[3].z), (short)f2bf(pwf[3].w) };
            *reinterpret_cast<short8_t*>(&Ws[wrow][wcol])     = w0;
            *reinterpret_cast<short8_t*>(&Ws[wrow][wcol + 8]) = w1;
        }
        __syncthreads();
        if (t + 1 < ZSTEPS) { loadA(t + 1); loadW(t + 1); }
#pragma unroll
        for (int kk = 0; kk < 64; kk += 32) {
            short8_t a[4], b[4];
#pragma unroll
            for (int i = 0; i < 4; ++i)
                a[i] = *reinterpret_cast<const short8_t*>(&As[wave * 64 + i * 16 + lr][kk + lk]);
#pragma unroll
            for (int j = 0; j < 4; ++j)
                b[j] = *reinterpret_cast<const short8_t*>(&Ws[j * 16 + lr][kk + lk]);
#pragma unroll
            for (int i = 0; i < 4; ++i)
#pragma unroll
                for (int j = 0; j < 4; ++j)
                    acc[i][j] = __builtin_amdgcn_mfma_f32_16x16x32_bf16(a[i], b[j], acc[i][j], 0, 0, 0);
        }
    }

    const int rbase = (lane >> 4) * 4;
#pragma unroll
    for (int i = 0; i < 4; ++i)
#pragma unroll
        for (int j = 0; j < 4; ++j) {
            const int col = n0 + j * 16 + lr;
#pragma unroll
            for (int r = 0; r < 4; ++r) {
                const int row = wave * 64 + i * 16 + rbase + r;
                Cz[(size_t)row * D1 + col] = acc[i][j][r];
            }
        }
}

// ---------------------------------------------------------------------------
// Sum split-K partials + b1 -> bf16 A2; also converts W2 -> bf16 (same
// element count, merged into the same launch).
// ---------------------------------------------------------------------------
__global__ __launch_bounds__(256) void k_fuse(const float* __restrict__ p,
                                              const float* __restrict__ b1,
                                              unsigned short* __restrict__ A2,
                                              const float* __restrict__ W2,
                                              unsigned short* __restrict__ W2b) {
    const int idx = (blockIdx.x * 256 + threadIdx.x) * 4;       // over 256*1024
    const int col = idx & (D1 - 1);
    const size_t S = (size_t)BATCH * D1;
    float4 bb = *reinterpret_cast<const float4*>(b1 + col);
    float sx = bb.x, sy = bb.y, sz = bb.z, sw = bb.w;
#pragma unroll
    for (int q = 0; q < NSPLIT; ++q) {
        float4 v = *reinterpret_cast<const float4*>(p + q * S + idx);
        sx += v.x; sy += v.y; sz += v.z; sw += v.w;
    }
    ushort4 o = { f2bf(sx), f2bf(sy), f2bf(sz), f2bf(sw) };
    *reinterpret_cast<ushort4*>(A2 + idx) = o;
    float4 wv = *reinterpret_cast<const float4*>(W2 + idx);
    ushort4 wo = { f2bf(wv.x), f2bf(wv.y), f2bf(wv.z), f2bf(wv.w) };
    *reinterpret_cast<ushort4*>(W2b + idx) = wo;
}

// ---------------------------------------------------------------------------
// Fused tail: out = sigmoid(A2 @ W2^T + b2) @ W3 + b3, h2 never materialized.
// 8 blocks x 512 threads (8 waves); wave w owns cols w*32..w*32+31.
// ---------------------------------------------------------------------------
__global__ __launch_bounds__(512) void k_tail(const unsigned short* __restrict__ A2,
                                              const unsigned short* __restrict__ W2b,
                                              const float* __restrict__ b2,
                                              const float* __restrict__ W3,
                                              const float* __restrict__ b3,
                                              float* __restrict__ out) {
    const int m0 = blockIdx.x * 32;
    __shared__ unsigned short As[32][72];
    __shared__ unsigned short Ws[256][72];
    __shared__ float red[8][32];

    const int tid  = threadIdx.x;
    const int wave = tid >> 6;
    const int lane = tid & 63;
    const int wc   = wave * 32;
    const int lr   = lane & 15;
    const int lk   = (lane >> 4) * 8;
    const int srow = tid >> 3;            // 0..63
    const int scol = (tid & 7) * 8;

    const unsigned short* Ap = A2 + (size_t)(m0 + srow) * D1 + scol;   // tid<256 only
    const unsigned short* Wp = W2b + (size_t)srow * D1 + scol;         // rows srow+64*it

    short8_t pa = {};
    short8_t pw[4];
    if (tid < 256) pa = *reinterpret_cast<const short8_t*>(Ap);
#pragma unroll
    for (int it = 0; it < 4; ++it)
        pw[it] = *reinterpret_cast<const short8_t*>(Wp + (size_t)it * 64 * D1);

    f32x4 acc[2][2] = {};

    for (int t = 0; t < 16; ++t) {
        __syncthreads();
        if (tid < 256) *reinterpret_cast<short8_t*>(&As[srow][scol]) = pa;
#pragma unroll
        for (int it = 0; it < 4; ++it)
            *reinterpret_cast<short8_t*>(&Ws[srow + it * 64][scol]) = pw[it];
        __syncthreads();
        if (t + 1 < 16) {
            const int ko = (t + 1) * 64;
            if (tid < 256) pa = *reinterpret_cast<const short8_t*>(Ap + ko);
#pragma unroll
            for (int it = 0; it < 4; ++it)
                pw[it] = *reinterpret_cast<const short8_t*>(Wp + (size_t)it * 64 * D1 + ko);
        }
#pragma unroll
        for (int kk = 0; kk < 64; kk += 32) {
            short8_t a0 = *reinterpret_cast<const short8_t*>(&As[lr][kk + lk]);
            short8_t a1 = *reinterpret_cast<const short8_t*>(&As[16 + lr][kk + lk]);
#pragma unroll
            for (int j = 0; j < 2; ++j) {
                short8_t bj = *reinterpret_cast<const short8_t*>(&Ws[wc + j * 16 + lr][kk + lk]);
                acc[0][j] = __builtin_amdgcn_mfma_f32_16x16x32_bf16(a0, bj, acc[0][j], 0, 0, 0);
                acc[1][j] = __builtin_amdgcn_mfma_f32_16x16x32_bf16(a1, bj, acc[1][j], 0, 0, 0);
            }
        }
    }

    float b2c[2], w3c[2];
#pragma unroll
    for (int j = 0; j < 2; ++j) {
        const int col = wc + j * 16 + lr;
        b2c[j] = b2[col];
        w3c[j] = W3[col];
    }
    const int rbase = (lane >> 4) * 4;
#pragma unroll
    for (int i = 0; i < 2; ++i) {
#pragma unroll
        for (int r = 0; r < 4; ++r) {
            float pv = 0.0f;
#pragma unroll
            for (int j = 0; j < 2; ++j) {
                const float h = acc[i][j][r] + b2c[j];
                pv += w3c[j] / (1.0f + __expf(-h));
            }
            pv += __shfl_xor(pv, 1);
            pv += __shfl_xor(pv, 2);
            pv += __shfl_xor(pv, 4);
            pv += __shfl_xor(pv, 8);
            if (lr == 0) red[wave][i * 16 + rbase + r] = pv;
        }
    }
    __syncthreads();
    if (tid < 32) {
        float s2 = 0.0f;
#pragma unroll
        for (int w = 0; w < 8; ++w) s2 += red[w][tid];
        out[m0 + tid] = s2 + b3[0];
    }
}

extern "C" void kernel_launch(void* const* d_in, const int* in_sizes, int n_in,
                              void* d_out, int out_size, void* d_ws, size_t ws_size,
                              hipStream_t stream) {
    const float* x     = (const float*)d_in[0];
    const float* sv    = (const float*)d_in[1];
    const float* gamma = (const float*)d_in[2];
    const float* beta  = (const float*)d_in[3];
    const float* W1    = (const float*)d_in[4];
    const float* b1    = (const float*)d_in[5];
    const float* W2    = (const float*)d_in[6];
    const float* b2    = (const float*)d_in[7];
    const float* W3    = (const float*)d_in[8];
    const float* b3    = (const float*)d_in[9];
    float* out = (float*)d_out;

    char* ws = (char*)d_ws;
    size_t off = 0;
    auto alloc = [&](size_t bytes) { char* p = ws + off; off = (off + bytes + 255) & ~(size_t)255; return p; };
    float*          g     = (float*)         alloc((size_t)BATCH * NBLKP * 4);       // 5.1 MB
    unsigned short* Ab    = (unsigned short*)alloc((size_t)BATCH * K1P * 2);         // 2.6 MB
    float*          out1p = (float*)         alloc((size_t)NSPLIT * BATCH * D1 * 4); // 16.8 MB
    unsigned short* A2b   = (unsigned short*)alloc((size_t)BATCH * D1 * 2);          // 0.5 MB
    unsigned short* W2b   = (unsigned short*)alloc((size_t)D2 * D1 * 2);             // 0.5 MB

    k_sparse<<<dim3((NBLK + 63) / 64, BATCH), 256, 0, stream>>>(x, sv, g);
    k_ln<<<dim3(BATCH), 256, 0, stream>>>(g, gamma, beta, Ab);
    k_gemm1<<<dim3(D1 / 64, NSPLIT), 256, 0, stream>>>(Ab, W1, out1p);
    k_fuse<<<dim3(BATCH * D1 / (256 * 4)), 256, 0, stream>>>(out1p, b1, A2b, W2, W2b);
    k_tail<<<dim3(BATCH / 32), 512, 0, stream>>>(A2b, W2b, b2, W3, b3, out);
}